// Round 1
// baseline (5767.966 us; speedup 1.0000x reference)
//
#include <hip/hip_runtime.h>

#define N_NODES 50000
#define N_EDGES 600000
#define D 128
#define NLAYERS 5
#define EPS 1e-5f

// h[n][d] = emb[x[n]][d]; agg = h (self-loop init)
__global__ void embed_kernel(const int* __restrict__ x, const float* __restrict__ emb,
                             float* __restrict__ h, float* __restrict__ agg) {
    int idx = blockIdx.x * blockDim.x + threadIdx.x;  // one float4 per thread
    if (idx >= N_NODES * (D / 4)) return;
    int n = idx >> 5;   // D/4 = 32
    int d4 = idx & 31;
    int op = x[n];
    float4 v = *(const float4*)(emb + op * D + d4 * 4);
    *(float4*)(h + (size_t)n * D + d4 * 4) = v;
    *(float4*)(agg + (size_t)n * D + d4 * 4) = v;
}

// agg[dst] += h[src] ; 32 threads per edge, one float4 each
__global__ void edge_kernel(const int* __restrict__ src, const int* __restrict__ dst,
                            const float* __restrict__ h, float* __restrict__ agg) {
    int tid = blockIdx.x * blockDim.x + threadIdx.x;
    int e = tid >> 5;
    if (e >= N_EDGES) return;
    int lane = tid & 31;
    int s = src[e];
    int t = dst[e];
    float4 v = *(const float4*)(h + (size_t)s * D + lane * 4);
    float* o = agg + (size_t)t * D + lane * 4;
    atomicAdd(o + 0, v.x);
    atomicAdd(o + 1, v.y);
    atomicAdd(o + 2, v.z);
    atomicAdd(o + 3, v.w);
}

// C[M,NC] = (relu?)(A[M,K] @ W[K,NC] + bias); optional per-column sum/sumsq into stats[2*NC]
// tile: 64 rows x 128 cols per block (256 threads, 4x8 micro-tile)
template <int K, int NC, bool RELU, bool STATS>
__global__ __launch_bounds__(256) void gemm_kernel(const float* __restrict__ A,
                                                   const float* __restrict__ W,
                                                   const float* __restrict__ bias,
                                                   float* __restrict__ C,
                                                   float* __restrict__ stats) {
    __shared__ float As[64][33];    // [row][k], +1 pad
    __shared__ float Ws[32][132];   // [k][col], +4 pad (keeps float4 alignment)
    const int tid = threadIdx.x;
    const int tx = tid & 15;   // col group (8 cols)
    const int ty = tid >> 4;   // row group (4 rows)
    const int r0 = blockIdx.x * 64;
    const int c0 = blockIdx.y * 128;

    float acc[4][8];
#pragma unroll
    for (int i = 0; i < 4; ++i)
#pragma unroll
        for (int j = 0; j < 8; ++j) acc[i][j] = 0.f;

    for (int k0 = 0; k0 < K; k0 += 32) {
        // A tile: 64 rows x 32 k
        {
            const int kq = tid & 7;     // which float4 along k
            const int rr0 = tid >> 3;   // 0..31
#pragma unroll
            for (int rr = rr0; rr < 64; rr += 32) {
                const int grow = r0 + rr;
                float4 a = make_float4(0.f, 0.f, 0.f, 0.f);
                if (grow < N_NODES) a = *(const float4*)(A + (size_t)grow * K + k0 + kq * 4);
                As[rr][kq * 4 + 0] = a.x;
                As[rr][kq * 4 + 1] = a.y;
                As[rr][kq * 4 + 2] = a.z;
                As[rr][kq * 4 + 3] = a.w;
            }
        }
        // W tile: 32 k x 128 cols
        {
            const int c4 = tid & 31;
            const int kk0 = tid >> 5;  // 0..7
#pragma unroll
            for (int kk = kk0; kk < 32; kk += 8) {
                float4 w = *(const float4*)(W + (size_t)(k0 + kk) * NC + c0 + c4 * 4);
                *(float4*)&Ws[kk][c4 * 4] = w;
            }
        }
        __syncthreads();
#pragma unroll
        for (int k = 0; k < 32; ++k) {
            float a[4];
#pragma unroll
            for (int i = 0; i < 4; ++i) a[i] = As[ty * 4 + i][k];
            float w[8];
            *(float4*)&w[0] = *(float4*)&Ws[k][tx * 8];
            *(float4*)&w[4] = *(float4*)&Ws[k][tx * 8 + 4];
#pragma unroll
            for (int i = 0; i < 4; ++i)
#pragma unroll
                for (int j = 0; j < 8; ++j) acc[i][j] += a[i] * w[j];
        }
        __syncthreads();
    }

    float bv[8];
    *(float4*)&bv[0] = *(const float4*)(bias + c0 + tx * 8);
    *(float4*)&bv[4] = *(const float4*)(bias + c0 + tx * 8 + 4);

    float colsum[8], colsq[8];
#pragma unroll
    for (int j = 0; j < 8; ++j) { colsum[j] = 0.f; colsq[j] = 0.f; }

#pragma unroll
    for (int i = 0; i < 4; ++i) {
        const int row = r0 + ty * 4 + i;
        if (row >= N_NODES) continue;
        float v[8];
#pragma unroll
        for (int j = 0; j < 8; ++j) {
            float z = acc[i][j] + bv[j];
            if constexpr (RELU) z = fmaxf(z, 0.f);
            v[j] = z;
            if constexpr (STATS) {
                colsum[j] += z;
                colsq[j] += z * z;
            }
        }
        *(float4*)(C + (size_t)row * NC + c0 + tx * 8) = *(float4*)&v[0];
        *(float4*)(C + (size_t)row * NC + c0 + tx * 8 + 4) = *(float4*)&v[4];
    }

    if constexpr (STATS) {
        float* red = &As[0][0];  // 2048 floats available (8448 B)
        __syncthreads();
#pragma unroll
        for (int j = 0; j < 8; ++j) red[ty * 128 + tx * 8 + j] = colsum[j];
        __syncthreads();
        if (tid < 128) {
            float s = 0.f;
#pragma unroll
            for (int t = 0; t < 16; ++t) s += red[t * 128 + tid];
            atomicAdd(&stats[c0 + tid], s);
        }
        __syncthreads();
#pragma unroll
        for (int j = 0; j < 8; ++j) red[ty * 128 + tx * 8 + j] = colsq[j];
        __syncthreads();
        if (tid < 128) {
            float s = 0.f;
#pragma unroll
            for (int t = 0; t < 16; ++t) s += red[t * 128 + tid];
            atomicAdd(&stats[NC + c0 + tid], s);
        }
    }
}

// BatchNorm (training stats from stats[]), optional relu; writes h (and agg=h for next layer)
template <bool LAST>
__global__ void bn_kernel(const float* __restrict__ z, const float* __restrict__ stats,
                          const float* __restrict__ gamma, const float* __restrict__ beta,
                          float* __restrict__ h, float* __restrict__ agg) {
    int idx = blockIdx.x * blockDim.x + threadIdx.x;  // one float4
    if (idx >= N_NODES * (D / 4)) return;
    int d4 = idx & 31;
    float4 zv = *(const float4*)(z + (size_t)idx * 4);
    float4 s = *(const float4*)(stats + d4 * 4);
    float4 sq = *(const float4*)(stats + D + d4 * 4);
    float4 g = *(const float4*)(gamma + d4 * 4);
    float4 b = *(const float4*)(beta + d4 * 4);
    const float invN = 1.0f / (float)N_NODES;
    float o[4];
    {
        float m = s.x * invN;
        float var = sq.x * invN - m * m;
        float r = rsqrtf(var + EPS);
        o[0] = g.x * (zv.x - m) * r + b.x;
    }
    {
        float m = s.y * invN;
        float var = sq.y * invN - m * m;
        float r = rsqrtf(var + EPS);
        o[1] = g.y * (zv.y - m) * r + b.y;
    }
    {
        float m = s.z * invN;
        float var = sq.z * invN - m * m;
        float r = rsqrtf(var + EPS);
        o[2] = g.z * (zv.z - m) * r + b.z;
    }
    {
        float m = s.w * invN;
        float var = sq.w * invN - m * m;
        float r = rsqrtf(var + EPS);
        o[3] = g.w * (zv.w - m) * r + b.w;
    }
    if constexpr (!LAST) {
#pragma unroll
        for (int j = 0; j < 4; ++j) o[j] = fmaxf(o[j], 0.f);
    }
    float4 o4 = make_float4(o[0], o[1], o[2], o[3]);
    *(float4*)(h + (size_t)idx * 4) = o4;
    if constexpr (!LAST) *(float4*)(agg + (size_t)idx * 4) = o4;
}

extern "C" void kernel_launch(void* const* d_in, const int* in_sizes, int n_in,
                              void* d_out, int out_size, void* d_ws, size_t ws_size,
                              hipStream_t stream) {
    const int* x_nodes = (const int*)d_in[0];
    const int* src = (const int*)d_in[1];
    const int* dst = (const int*)d_in[2];
    const float* emb = (const float*)d_in[3];
    const float* W1 = (const float*)d_in[4];
    const float* b1 = (const float*)d_in[5];
    const float* W2 = (const float*)d_in[6];
    const float* b2 = (const float*)d_in[7];
    const float* gamma = (const float*)d_in[8];
    const float* beta = (const float*)d_in[9];

    float* h = (float*)d_out;  // h lives in d_out (final layer writes the answer here)
    float* agg = (float*)d_ws;                       // N*D floats (also holds z)
    float* z1 = agg + (size_t)N_NODES * D;           // N*2D floats
    float* stats = z1 + (size_t)N_NODES * 2 * D;     // 2*D floats

    dim3 blk(256);
    embed_kernel<<<(N_NODES * 32 + 255) / 256, blk, 0, stream>>>(x_nodes, emb, h, agg);

    const int gemm_gx = (N_NODES + 63) / 64;  // 782
    for (int l = 0; l < NLAYERS; ++l) {
        edge_kernel<<<(N_EDGES * 32) / 256, blk, 0, stream>>>(src, dst, h, agg);
        gemm_kernel<128, 256, true, false><<<dim3(gemm_gx, 2), blk, 0, stream>>>(
            agg, W1 + (size_t)l * D * 2 * D, b1 + l * 2 * D, z1, nullptr);
        hipMemsetAsync(stats, 0, 2 * D * sizeof(float), stream);
        gemm_kernel<256, 128, false, true><<<dim3(gemm_gx, 1), blk, 0, stream>>>(
            z1, W2 + (size_t)l * 2 * D * D, b2 + l * D, agg, stats);
        if (l < NLAYERS - 1) {
            bn_kernel<false><<<(N_NODES * 32 + 255) / 256, blk, 0, stream>>>(
                agg, stats, gamma + l * D, beta + l * D, h, agg);
        } else {
            bn_kernel<true><<<(N_NODES * 32 + 255) / 256, blk, 0, stream>>>(
                agg, stats, gamma + l * D, beta + l * D, h, nullptr);
        }
    }
    (void)in_sizes; (void)n_in; (void)out_size; (void)ws_size;
}

// Round 2
// 989.046 us; speedup vs baseline: 5.8319x; 5.8319x over previous
//
#include <hip/hip_runtime.h>

#define N_NODES 50000
#define N_EDGES 600000
#define D 128
#define NLAYERS 5
#define EPS 1e-5f

// ---------------- CSR build ----------------

__global__ void deg_kernel(const int* __restrict__ dst, int* __restrict__ deg) {
    int e = blockIdx.x * blockDim.x + threadIdx.x;
    if (e < N_EDGES) atomicAdd(&deg[dst[e]], 1);
}

// exclusive scan over deg -> offsets (per-block partials), block totals -> blocksums
__global__ __launch_bounds__(1024) void scan_block_kernel(const int* __restrict__ deg,
                                                          int* __restrict__ offsets,
                                                          int* __restrict__ blocksums) {
    __shared__ int tmp[1024];
    int i = blockIdx.x * 1024 + threadIdx.x;
    int v = (i < N_NODES) ? deg[i] : 0;
    tmp[threadIdx.x] = v;
    __syncthreads();
#pragma unroll
    for (int off = 1; off < 1024; off <<= 1) {
        int t = (threadIdx.x >= off) ? tmp[threadIdx.x - off] : 0;
        __syncthreads();
        tmp[threadIdx.x] += t;
        __syncthreads();
    }
    if (i < N_NODES) offsets[i] = tmp[threadIdx.x] - v;  // exclusive
    if (threadIdx.x == 1023) blocksums[blockIdx.x] = tmp[1023];
}

__global__ void scan_sums_kernel(int* __restrict__ blocksums, int nb, int* __restrict__ offsets) {
    if (threadIdx.x == 0 && blockIdx.x == 0) {
        int run = 0;
        for (int i = 0; i < nb; ++i) {
            int t = blocksums[i];
            blocksums[i] = run;
            run += t;
        }
        offsets[N_NODES] = N_EDGES;
    }
}

__global__ __launch_bounds__(1024) void scan_add_kernel(int* __restrict__ offsets,
                                                        const int* __restrict__ blocksums) {
    int i = blockIdx.x * 1024 + threadIdx.x;
    if (i < N_NODES) offsets[i] += blocksums[blockIdx.x];
}

__global__ void scatter_kernel(const int* __restrict__ src, const int* __restrict__ dst,
                               int* __restrict__ cursor, int* __restrict__ sorted_src) {
    int e = blockIdx.x * blockDim.x + threadIdx.x;
    if (e >= N_EDGES) return;
    int t = dst[e];
    int pos = atomicAdd(&cursor[t], 1);
    sorted_src[pos] = src[e];
}

// ---------------- model kernels ----------------

// h[n][d] = emb[x[n]][d]
__global__ void embed_kernel(const int* __restrict__ x, const float* __restrict__ emb,
                             float* __restrict__ h) {
    int idx = blockIdx.x * blockDim.x + threadIdx.x;  // one float4 per thread
    if (idx >= N_NODES * (D / 4)) return;
    int n = idx >> 5;   // D/4 = 32
    int d4 = idx & 31;
    int op = x[n];
    *(float4*)(h + (size_t)n * D + d4 * 4) = *(const float4*)(emb + op * D + d4 * 4);
}

// pull aggregation: agg[n] = h[n] + sum_{s in in(n)} h[s]
// one 64-lane wave per node; each lane owns a float2 of the row
__global__ __launch_bounds__(256) void agg_kernel(const int* __restrict__ offsets,
                                                  const int* __restrict__ sorted_src,
                                                  const float* __restrict__ h,
                                                  float* __restrict__ agg) {
    int node = blockIdx.x * 4 + (threadIdx.x >> 6);
    if (node >= N_NODES) return;
    int lane = threadIdx.x & 63;
    const float* hp = h + (size_t)node * D + lane * 2;
    float sx = hp[0], sy = hp[1];  // self loop
    int j = offsets[node];
    const int end = offsets[node + 1];
    for (; j + 4 <= end; j += 4) {
        int s0 = sorted_src[j + 0];
        int s1 = sorted_src[j + 1];
        int s2 = sorted_src[j + 2];
        int s3 = sorted_src[j + 3];
        const float* p0 = h + (size_t)s0 * D + lane * 2;
        const float* p1 = h + (size_t)s1 * D + lane * 2;
        const float* p2 = h + (size_t)s2 * D + lane * 2;
        const float* p3 = h + (size_t)s3 * D + lane * 2;
        float ax = p0[0], ay = p0[1];
        float bx = p1[0], by = p1[1];
        float cx = p2[0], cy = p2[1];
        float dx = p3[0], dy = p3[1];
        sx += ax + bx + cx + dx;
        sy += ay + by + cy + dy;
    }
    for (; j < end; ++j) {
        const float* p = h + (size_t)sorted_src[j] * D + lane * 2;
        sx += p[0];
        sy += p[1];
    }
    float* op = agg + (size_t)node * D + lane * 2;
    op[0] = sx;
    op[1] = sy;
}

// C[M,NC] = (relu?)(A[M,K] @ W[K,NC] + bias); optional per-column sum/sumsq into stats[2*NC]
template <int K, int NC, bool RELU, bool STATS>
__global__ __launch_bounds__(256) void gemm_kernel(const float* __restrict__ A,
                                                   const float* __restrict__ W,
                                                   const float* __restrict__ bias,
                                                   float* __restrict__ C,
                                                   float* __restrict__ stats) {
    __shared__ float As[64][33];    // [row][k], +1 pad
    __shared__ float Ws[32][132];   // [k][col], +4 pad
    const int tid = threadIdx.x;
    const int tx = tid & 15;   // col group (8 cols)
    const int ty = tid >> 4;   // row group (4 rows)
    const int r0 = blockIdx.x * 64;
    const int c0 = blockIdx.y * 128;

    float acc[4][8];
#pragma unroll
    for (int i = 0; i < 4; ++i)
#pragma unroll
        for (int j = 0; j < 8; ++j) acc[i][j] = 0.f;

    for (int k0 = 0; k0 < K; k0 += 32) {
        {
            const int kq = tid & 7;
            const int rr0 = tid >> 3;
#pragma unroll
            for (int rr = rr0; rr < 64; rr += 32) {
                const int grow = r0 + rr;
                float4 a = make_float4(0.f, 0.f, 0.f, 0.f);
                if (grow < N_NODES) a = *(const float4*)(A + (size_t)grow * K + k0 + kq * 4);
                As[rr][kq * 4 + 0] = a.x;
                As[rr][kq * 4 + 1] = a.y;
                As[rr][kq * 4 + 2] = a.z;
                As[rr][kq * 4 + 3] = a.w;
            }
        }
        {
            const int c4 = tid & 31;
            const int kk0 = tid >> 5;
#pragma unroll
            for (int kk = kk0; kk < 32; kk += 8) {
                float4 w = *(const float4*)(W + (size_t)(k0 + kk) * NC + c0 + c4 * 4);
                *(float4*)&Ws[kk][c4 * 4] = w;
            }
        }
        __syncthreads();
#pragma unroll
        for (int k = 0; k < 32; ++k) {
            float a[4];
#pragma unroll
            for (int i = 0; i < 4; ++i) a[i] = As[ty * 4 + i][k];
            float w[8];
            *(float4*)&w[0] = *(float4*)&Ws[k][tx * 8];
            *(float4*)&w[4] = *(float4*)&Ws[k][tx * 8 + 4];
#pragma unroll
            for (int i = 0; i < 4; ++i)
#pragma unroll
                for (int j = 0; j < 8; ++j) acc[i][j] += a[i] * w[j];
        }
        __syncthreads();
    }

    float bv[8];
    *(float4*)&bv[0] = *(const float4*)(bias + c0 + tx * 8);
    *(float4*)&bv[4] = *(const float4*)(bias + c0 + tx * 8 + 4);

    float colsum[8], colsq[8];
#pragma unroll
    for (int j = 0; j < 8; ++j) { colsum[j] = 0.f; colsq[j] = 0.f; }

#pragma unroll
    for (int i = 0; i < 4; ++i) {
        const int row = r0 + ty * 4 + i;
        if (row >= N_NODES) continue;
        float v[8];
#pragma unroll
        for (int j = 0; j < 8; ++j) {
            float z = acc[i][j] + bv[j];
            if constexpr (RELU) z = fmaxf(z, 0.f);
            v[j] = z;
            if constexpr (STATS) {
                colsum[j] += z;
                colsq[j] += z * z;
            }
        }
        *(float4*)(C + (size_t)row * NC + c0 + tx * 8) = *(float4*)&v[0];
        *(float4*)(C + (size_t)row * NC + c0 + tx * 8 + 4) = *(float4*)&v[4];
    }

    if constexpr (STATS) {
        float* red = &As[0][0];
        __syncthreads();
#pragma unroll
        for (int j = 0; j < 8; ++j) red[ty * 128 + tx * 8 + j] = colsum[j];
        __syncthreads();
        if (tid < 128) {
            float s = 0.f;
#pragma unroll
            for (int t = 0; t < 16; ++t) s += red[t * 128 + tid];
            atomicAdd(&stats[c0 + tid], s);
        }
        __syncthreads();
#pragma unroll
        for (int j = 0; j < 8; ++j) red[ty * 128 + tx * 8 + j] = colsq[j];
        __syncthreads();
        if (tid < 128) {
            float s = 0.f;
#pragma unroll
            for (int t = 0; t < 16; ++t) s += red[t * 128 + tid];
            atomicAdd(&stats[NC + c0 + tid], s);
        }
    }
}

// BatchNorm (training stats), relu for non-last layers; writes h
template <bool LAST>
__global__ void bn_kernel(const float* __restrict__ z, const float* __restrict__ stats,
                          const float* __restrict__ gamma, const float* __restrict__ beta,
                          float* __restrict__ h) {
    int idx = blockIdx.x * blockDim.x + threadIdx.x;  // one float4
    if (idx >= N_NODES * (D / 4)) return;
    int d4 = idx & 31;
    float4 zv = *(const float4*)(z + (size_t)idx * 4);
    float4 s = *(const float4*)(stats + d4 * 4);
    float4 sq = *(const float4*)(stats + D + d4 * 4);
    float4 g = *(const float4*)(gamma + d4 * 4);
    float4 b = *(const float4*)(beta + d4 * 4);
    const float invN = 1.0f / (float)N_NODES;
    float o[4];
    float zz[4] = {zv.x, zv.y, zv.z, zv.w};
    float ss[4] = {s.x, s.y, s.z, s.w};
    float qq[4] = {sq.x, sq.y, sq.z, sq.w};
    float gg[4] = {g.x, g.y, g.z, g.w};
    float bb[4] = {b.x, b.y, b.z, b.w};
#pragma unroll
    for (int j = 0; j < 4; ++j) {
        float m = ss[j] * invN;
        float var = qq[j] * invN - m * m;
        float r = rsqrtf(var + EPS);
        o[j] = gg[j] * (zz[j] - m) * r + bb[j];
        if constexpr (!LAST) o[j] = fmaxf(o[j], 0.f);
    }
    *(float4*)(h + (size_t)idx * 4) = make_float4(o[0], o[1], o[2], o[3]);
}

extern "C" void kernel_launch(void* const* d_in, const int* in_sizes, int n_in,
                              void* d_out, int out_size, void* d_ws, size_t ws_size,
                              hipStream_t stream) {
    const int* x_nodes = (const int*)d_in[0];
    const int* src = (const int*)d_in[1];
    const int* dst = (const int*)d_in[2];
    const float* emb = (const float*)d_in[3];
    const float* W1 = (const float*)d_in[4];
    const float* b1 = (const float*)d_in[5];
    const float* W2 = (const float*)d_in[6];
    const float* b2 = (const float*)d_in[7];
    const float* gamma = (const float*)d_in[8];
    const float* beta = (const float*)d_in[9];

    float* h = (float*)d_out;                        // [N,D]
    float* agg = (float*)d_ws;                       // N*D floats (also holds z)
    float* z1 = agg + (size_t)N_NODES * D;           // N*2D floats
    float* stats = z1 + (size_t)N_NODES * 2 * D;     // 512 floats
    int* deg = (int*)(stats + 512);                  // N
    int* offsets = deg + N_NODES;                    // N+1
    int* cursor = offsets + N_NODES + 1;             // N
    int* blocksums = cursor + N_NODES;               // 64
    int* sorted_src = blocksums + 64;                // E

    dim3 blk(256);
    const int nb_scan = (N_NODES + 1023) / 1024;  // 49
    const int nb_edge = (N_EDGES + 255) / 256;

    // ---- CSR build (once per call, reused across 5 layers) ----
    hipMemsetAsync(deg, 0, N_NODES * sizeof(int), stream);
    deg_kernel<<<nb_edge, blk, 0, stream>>>(dst, deg);
    scan_block_kernel<<<nb_scan, 1024, 0, stream>>>(deg, offsets, blocksums);
    scan_sums_kernel<<<1, 64, 0, stream>>>(blocksums, nb_scan, offsets);
    scan_add_kernel<<<nb_scan, 1024, 0, stream>>>(offsets, blocksums);
    hipMemcpyAsync(cursor, offsets, N_NODES * sizeof(int), hipMemcpyDeviceToDevice, stream);
    scatter_kernel<<<nb_edge, blk, 0, stream>>>(src, dst, cursor, sorted_src);

    // ---- model ----
    embed_kernel<<<(N_NODES * 32 + 255) / 256, blk, 0, stream>>>(x_nodes, emb, h);

    const int gemm_gx = (N_NODES + 63) / 64;  // 782
    for (int l = 0; l < NLAYERS; ++l) {
        agg_kernel<<<(N_NODES + 3) / 4, blk, 0, stream>>>(offsets, sorted_src, h, agg);
        gemm_kernel<128, 256, true, false><<<dim3(gemm_gx, 2), blk, 0, stream>>>(
            agg, W1 + (size_t)l * D * 2 * D, b1 + l * 2 * D, z1, nullptr);
        hipMemsetAsync(stats, 0, 2 * D * sizeof(float), stream);
        gemm_kernel<256, 128, false, true><<<dim3(gemm_gx, 1), blk, 0, stream>>>(
            z1, W2 + (size_t)l * 2 * D * D, b2 + l * D, agg, stats);
        if (l < NLAYERS - 1) {
            bn_kernel<false><<<(N_NODES * 32 + 255) / 256, blk, 0, stream>>>(
                agg, stats, gamma + l * D, beta + l * D, h);
        } else {
            bn_kernel<true><<<(N_NODES * 32 + 255) / 256, blk, 0, stream>>>(
                agg, stats, gamma + l * D, beta + l * D, h);
        }
    }
    (void)in_sizes; (void)n_in; (void)out_size; (void)ws_size;
}

// Round 3
// 642.242 us; speedup vs baseline: 8.9810x; 1.5400x over previous
//
#include <hip/hip_runtime.h>

#define N_NODES 50000
#define N_EDGES 600000
#define D 128
#define NLAYERS 5
#define EPS 1e-5f

typedef _Float16 f16;
typedef f16 f16x8 __attribute__((ext_vector_type(8)));
typedef f16 f16x4 __attribute__((ext_vector_type(4)));
typedef f16 f16x2 __attribute__((ext_vector_type(2)));
typedef float f32x4 __attribute__((ext_vector_type(4)));

// ---------------- CSR build ----------------

__global__ void deg_kernel(const int* __restrict__ dst, int* __restrict__ deg) {
    int e = blockIdx.x * blockDim.x + threadIdx.x;
    if (e < N_EDGES) atomicAdd(&deg[dst[e]], 1);
}

__global__ __launch_bounds__(1024) void scan_block_kernel(const int* __restrict__ deg,
                                                          int* __restrict__ offsets,
                                                          int* __restrict__ blocksums) {
    __shared__ int tmp[1024];
    int i = blockIdx.x * 1024 + threadIdx.x;
    int v = (i < N_NODES) ? deg[i] : 0;
    tmp[threadIdx.x] = v;
    __syncthreads();
#pragma unroll
    for (int off = 1; off < 1024; off <<= 1) {
        int t = (threadIdx.x >= off) ? tmp[threadIdx.x - off] : 0;
        __syncthreads();
        tmp[threadIdx.x] += t;
        __syncthreads();
    }
    if (i < N_NODES) offsets[i] = tmp[threadIdx.x] - v;  // exclusive
    if (threadIdx.x == 1023) blocksums[blockIdx.x] = tmp[1023];
}

__global__ void scan_sums_kernel(int* __restrict__ blocksums, int nb, int* __restrict__ offsets) {
    if (threadIdx.x == 0 && blockIdx.x == 0) {
        int run = 0;
        for (int i = 0; i < nb; ++i) {
            int t = blocksums[i];
            blocksums[i] = run;
            run += t;
        }
        offsets[N_NODES] = N_EDGES;
    }
}

__global__ __launch_bounds__(1024) void scan_add_kernel(int* __restrict__ offsets,
                                                        const int* __restrict__ blocksums) {
    int i = blockIdx.x * 1024 + threadIdx.x;
    if (i < N_NODES) offsets[i] += blocksums[blockIdx.x];
}

__global__ void scatter_kernel(const int* __restrict__ src, const int* __restrict__ dst,
                               int* __restrict__ cursor, int* __restrict__ sorted_src) {
    int e = blockIdx.x * blockDim.x + threadIdx.x;
    if (e >= N_EDGES) return;
    int t = dst[e];
    int pos = atomicAdd(&cursor[t], 1);
    sorted_src[pos] = src[e];
}

// ---------------- weight convert: w1t[l][n][k] = W1[l][k][n] (f16), same for w2t ----------------

__global__ void convert_w_kernel(const float* __restrict__ W1, const float* __restrict__ W2,
                                 f16* __restrict__ w1t, f16* __restrict__ w2t) {
    int idx = blockIdx.x * blockDim.x + threadIdx.x;
    const int per_layer = 2 * D * D;  // 32768
    if (idx >= NLAYERS * per_layer) return;
    int l = idx / per_layer;
    int rem = idx - l * per_layer;
    {   // w1t: [2D][D], from W1[l][D][2D]
        int n = rem / D, k = rem - n * D;
        w1t[idx] = (f16)W1[(size_t)l * per_layer + (size_t)k * (2 * D) + n];
    }
    {   // w2t: [D][2D], from W2[l][2D][D]
        int n = rem / (2 * D), k = rem - n * (2 * D);
        w2t[idx] = (f16)W2[(size_t)l * per_layer + (size_t)k * D + n];
    }
}

// ---------------- model kernels ----------------

// h_h[n][d] = (f16) emb[x[n]][d]
__global__ void embed_kernel(const int* __restrict__ x, const float* __restrict__ emb,
                             f16* __restrict__ h_h) {
    int idx = blockIdx.x * blockDim.x + threadIdx.x;  // one 8-elem chunk
    if (idx >= N_NODES * (D / 8)) return;
    int n = idx >> 4;   // D/8 = 16
    int d8 = idx & 15;
    const float* e = emb + x[n] * D + d8 * 8;
    f16x8 v;
#pragma unroll
    for (int j = 0; j < 8; ++j) v[j] = (f16)e[j];
    *(f16x8*)(h_h + (size_t)n * D + d8 * 8) = v;
}

// pull aggregation: agg_h[n] = (f16)( h_h[n] + sum_{s in in(n)} h_h[s] ), accumulate fp32
// one 64-lane wave per node; lane owns 2 features (f16x2 = 4B)
__global__ __launch_bounds__(256) void agg_kernel(const int* __restrict__ offsets,
                                                  const int* __restrict__ sorted_src,
                                                  const f16* __restrict__ h_h,
                                                  f16* __restrict__ agg_h) {
    int node = blockIdx.x * 4 + (threadIdx.x >> 6);
    if (node >= N_NODES) return;
    int lane = threadIdx.x & 63;
    f16x2 hv = *(const f16x2*)(h_h + (size_t)node * D + lane * 2);
    float sx = (float)hv[0], sy = (float)hv[1];  // self loop
    int j = offsets[node];
    const int end = offsets[node + 1];
    for (; j + 4 <= end; j += 4) {
        int s0 = sorted_src[j + 0];
        int s1 = sorted_src[j + 1];
        int s2 = sorted_src[j + 2];
        int s3 = sorted_src[j + 3];
        f16x2 a = *(const f16x2*)(h_h + (size_t)s0 * D + lane * 2);
        f16x2 b = *(const f16x2*)(h_h + (size_t)s1 * D + lane * 2);
        f16x2 c = *(const f16x2*)(h_h + (size_t)s2 * D + lane * 2);
        f16x2 d = *(const f16x2*)(h_h + (size_t)s3 * D + lane * 2);
        sx += (float)a[0] + (float)b[0] + (float)c[0] + (float)d[0];
        sy += (float)a[1] + (float)b[1] + (float)c[1] + (float)d[1];
    }
    for (; j < end; ++j) {
        f16x2 a = *(const f16x2*)(h_h + (size_t)sorted_src[j] * D + lane * 2);
        sx += (float)a[0];
        sy += (float)a[1];
    }
    f16x2 o;
    o[0] = (f16)sx;
    o[1] = (f16)sy;
    *(f16x2*)(agg_h + (size_t)node * D + lane * 2) = o;
}

// MFMA GEMM: C[M,NC] = A[M,K] @ Wt[NC,K]^T + bias
// FIRST: relu, store f16. !FIRST: store f32 + column stats (sum, sumsq) into stats[2*NC] (grid.y==1).
// Block: 256 threads = 4 waves (2x2), tile 64 rows x 128 cols; per-wave 32x64 (2x4 16x16 frags).
template <int K, int NC, bool FIRST>
__global__ __launch_bounds__(256) void mfma_gemm(const f16* __restrict__ A,
                                                 const f16* __restrict__ Wt,
                                                 const float* __restrict__ bias,
                                                 void* __restrict__ Cout,
                                                 float* __restrict__ stats) {
    __shared__ __align__(16) f16 As[64 * K];
    __shared__ float sred[FIRST ? 1 : 2 * NC];
    const int tid = threadIdx.x;
    const int r0 = blockIdx.x * 64;
    const int c0 = blockIdx.y * 128;
    const int wave = tid >> 6, lane = tid & 63;
    const int wr = wave >> 1, wc = wave & 1;
    const int l15 = lane & 15, l4 = lane >> 4;

    if constexpr (!FIRST) {
        for (int i = tid; i < 2 * NC; i += 256) sred[i] = 0.f;
    }

    // stage A tile (64 x K halfs), XOR swizzle rows: byte ^= (r&7)<<4
    {
        constexpr int CPR = K / 8;  // 16B chunks per row
        for (int c = tid; c < 64 * CPR; c += 256) {
            int r = c / CPR, kc = c - r * CPR;
            f16x8 v = {};
            int grow = r0 + r;
            if (grow < N_NODES) v = *(const f16x8*)(A + (size_t)grow * K + kc * 8);
            int byte = ((r * K + kc * 8) * 2) ^ ((r & 7) << 4);
            *(f16x8*)((char*)As + byte) = v;
        }
    }

    // B fragments for a 128-wide K chunk live in registers (16 frags = 64 VGPR)
    const f16* Wb = Wt + (size_t)(c0 + wc * 64 + l15) * K + l4 * 8;
    f16x8 bfr[4][4];
#pragma unroll
    for (int cf = 0; cf < 4; ++cf)
#pragma unroll
        for (int kk = 0; kk < 4; ++kk)
            bfr[cf][kk] = *(const f16x8*)(Wb + cf * 16 * K + kk * 32);

    f32x4 acc[2][4] = {};
    __syncthreads();

    const int rbase = wr * 32;
#pragma unroll
    for (int chunk = 0; chunk < K / 128; ++chunk) {
        if (chunk > 0) {
#pragma unroll
            for (int cf = 0; cf < 4; ++cf)
#pragma unroll
                for (int kk = 0; kk < 4; ++kk)
                    bfr[cf][kk] = *(const f16x8*)(Wb + cf * 16 * K + chunk * 128 + kk * 32);
        }
#pragma unroll
        for (int kk = 0; kk < 4; ++kk) {
            const int k = chunk * 128 + kk * 32 + l4 * 8;
            f16x8 a[2];
#pragma unroll
            for (int fm = 0; fm < 2; ++fm) {
                const int r = rbase + fm * 16 + l15;
                const int byte = ((r * K + k) * 2) ^ ((r & 7) << 4);
                a[fm] = *(const f16x8*)((const char*)As + byte);
            }
#pragma unroll
            for (int fm = 0; fm < 2; ++fm)
#pragma unroll
                for (int cf = 0; cf < 4; ++cf)
                    acc[fm][cf] = __builtin_amdgcn_mfma_f32_16x16x32_f16(
                        a[fm], bfr[cf][kk], acc[fm][cf], 0, 0, 0);
        }
    }

    float bv[4];
#pragma unroll
    for (int cf = 0; cf < 4; ++cf) bv[cf] = bias[c0 + wc * 64 + cf * 16 + l15];

    if constexpr (FIRST) {
        f16* C = (f16*)Cout;
#pragma unroll
        for (int fm = 0; fm < 2; ++fm)
#pragma unroll
            for (int cf = 0; cf < 4; ++cf) {
                const int col = c0 + wc * 64 + cf * 16 + l15;
#pragma unroll
                for (int j = 0; j < 4; ++j) {
                    const int row = r0 + rbase + fm * 16 + l4 * 4 + j;
                    if (row < N_NODES) {
                        float z = fmaxf(acc[fm][cf][j] + bv[cf], 0.f);
                        C[(size_t)row * NC + col] = (f16)z;
                    }
                }
            }
    } else {
        float* C = (float*)Cout;
        float cs[4], cq[4];
#pragma unroll
        for (int cf = 0; cf < 4; ++cf) { cs[cf] = 0.f; cq[cf] = 0.f; }
#pragma unroll
        for (int fm = 0; fm < 2; ++fm)
#pragma unroll
            for (int cf = 0; cf < 4; ++cf) {
                const int col = c0 + wc * 64 + cf * 16 + l15;
#pragma unroll
                for (int j = 0; j < 4; ++j) {
                    const int row = r0 + rbase + fm * 16 + l4 * 4 + j;
                    if (row < N_NODES) {
                        float z = acc[fm][cf][j] + bv[cf];
                        C[(size_t)row * NC + col] = z;
                        cs[cf] += z;
                        cq[cf] += z * z;
                    }
                }
            }
        // reduce over the 4 row-groups (lanes l, l^16, l^32 share a column)
#pragma unroll
        for (int cf = 0; cf < 4; ++cf) {
            float s = cs[cf], q = cq[cf];
            s += __shfl_xor(s, 16, 64);
            q += __shfl_xor(q, 16, 64);
            s += __shfl_xor(s, 32, 64);
            q += __shfl_xor(q, 32, 64);
            if (l4 == 0) {
                const int col = wc * 64 + cf * 16 + l15;  // c0 == 0 for stats path
                atomicAdd(&sred[col], s);
                atomicAdd(&sred[NC + col], q);
            }
        }
        __syncthreads();
        for (int i = tid; i < 2 * NC; i += 256) atomicAdd(&stats[i], sred[i]);
    }
}

// BatchNorm (training stats); !LAST: relu -> h_h (f16). LAST: no relu -> h (f32, d_out).
template <bool LAST>
__global__ void bn_kernel(const float* __restrict__ z, const float* __restrict__ stats,
                          const float* __restrict__ gamma, const float* __restrict__ beta,
                          float* __restrict__ hout, f16* __restrict__ h_h) {
    int idx = blockIdx.x * blockDim.x + threadIdx.x;  // one float4
    if (idx >= N_NODES * (D / 4)) return;
    int d4 = idx & 31;
    float4 zv = *(const float4*)(z + (size_t)idx * 4);
    float4 s = *(const float4*)(stats + d4 * 4);
    float4 sq = *(const float4*)(stats + D + d4 * 4);
    float4 g = *(const float4*)(gamma + d4 * 4);
    float4 b = *(const float4*)(beta + d4 * 4);
    const float invN = 1.0f / (float)N_NODES;
    float zz[4] = {zv.x, zv.y, zv.z, zv.w};
    float ss[4] = {s.x, s.y, s.z, s.w};
    float qq[4] = {sq.x, sq.y, sq.z, sq.w};
    float gg[4] = {g.x, g.y, g.z, g.w};
    float bb[4] = {b.x, b.y, b.z, b.w};
    float o[4];
#pragma unroll
    for (int j = 0; j < 4; ++j) {
        float m = ss[j] * invN;
        float var = qq[j] * invN - m * m;
        float r = rsqrtf(var + EPS);
        o[j] = gg[j] * (zz[j] - m) * r + bb[j];
    }
    if constexpr (LAST) {
        *(float4*)(hout + (size_t)idx * 4) = make_float4(o[0], o[1], o[2], o[3]);
    } else {
        f16x4 v;
#pragma unroll
        for (int j = 0; j < 4; ++j) v[j] = (f16)fmaxf(o[j], 0.f);
        *(f16x4*)(h_h + (size_t)idx * 4) = v;
    }
}

extern "C" void kernel_launch(void* const* d_in, const int* in_sizes, int n_in,
                              void* d_out, int out_size, void* d_ws, size_t ws_size,
                              hipStream_t stream) {
    const int* x_nodes = (const int*)d_in[0];
    const int* src = (const int*)d_in[1];
    const int* dst = (const int*)d_in[2];
    const float* emb = (const float*)d_in[3];
    const float* W1 = (const float*)d_in[4];
    const float* b1 = (const float*)d_in[5];
    const float* W2 = (const float*)d_in[6];
    const float* b2 = (const float*)d_in[7];
    const float* gamma = (const float*)d_in[8];
    const float* beta = (const float*)d_in[9];

    float* h = (float*)d_out;  // final fp32 output

    // workspace layout (z2 and agg_h share a region: disjoint lifetimes)
    float* z2 = (float*)d_ws;                                   // N*D f32
    f16* agg_h = (f16*)d_ws;                                    // N*D f16 (alias)
    f16* z1h = (f16*)(z2 + (size_t)N_NODES * D);                // N*2D f16
    f16* h_h = z1h + (size_t)N_NODES * 2 * D;                   // N*D f16
    f16* w1t = h_h + (size_t)N_NODES * D;                       // L*2D*D f16
    f16* w2t = w1t + (size_t)NLAYERS * 2 * D * D;               // L*D*2D f16
    float* stats = (float*)(w2t + (size_t)NLAYERS * 2 * D * D); // 2*D f32
    int* deg = (int*)(stats + 2 * D);                           // N
    int* offsets = deg + N_NODES;                               // N+1
    int* cursor = offsets + N_NODES + 1;                        // N
    int* blocksums = cursor + N_NODES;                          // 64
    int* sorted_src = blocksums + 64;                           // E

    dim3 blk(256);
    const int nb_scan = (N_NODES + 1023) / 1024;  // 49
    const int nb_edge = (N_EDGES + 255) / 256;

    // ---- one-time per call: weights + CSR ----
    convert_w_kernel<<<(NLAYERS * 2 * D * D + 255) / 256, blk, 0, stream>>>(W1, W2, w1t, w2t);
    hipMemsetAsync(deg, 0, N_NODES * sizeof(int), stream);
    deg_kernel<<<nb_edge, blk, 0, stream>>>(dst, deg);
    scan_block_kernel<<<nb_scan, 1024, 0, stream>>>(deg, offsets, blocksums);
    scan_sums_kernel<<<1, 64, 0, stream>>>(blocksums, nb_scan, offsets);
    scan_add_kernel<<<nb_scan, 1024, 0, stream>>>(offsets, blocksums);
    hipMemcpyAsync(cursor, offsets, N_NODES * sizeof(int), hipMemcpyDeviceToDevice, stream);
    scatter_kernel<<<nb_edge, blk, 0, stream>>>(src, dst, cursor, sorted_src);

    // ---- model ----
    embed_kernel<<<(N_NODES * 16 + 255) / 256, blk, 0, stream>>>(x_nodes, emb, h_h);

    const int gemm_gx = (N_NODES + 63) / 64;  // 782
    for (int l = 0; l < NLAYERS; ++l) {
        agg_kernel<<<(N_NODES + 3) / 4, blk, 0, stream>>>(offsets, sorted_src, h_h, agg_h);
        mfma_gemm<128, 256, true><<<dim3(gemm_gx, 2), blk, 0, stream>>>(
            agg_h, w1t + (size_t)l * 2 * D * D, b1 + l * 2 * D, z1h, nullptr);
        hipMemsetAsync(stats, 0, 2 * D * sizeof(float), stream);
        mfma_gemm<256, 128, false><<<dim3(gemm_gx, 1), blk, 0, stream>>>(
            z1h, w2t + (size_t)l * 2 * D * D, b2 + l * D, z2, stats);
        if (l < NLAYERS - 1) {
            bn_kernel<false><<<(N_NODES * 32 + 255) / 256, blk, 0, stream>>>(
                z2, stats, gamma + l * D, beta + l * D, nullptr, h_h);
        } else {
            bn_kernel<true><<<(N_NODES * 32 + 255) / 256, blk, 0, stream>>>(
                z2, stats, gamma + l * D, beta + l * D, h, nullptr);
        }
    }
    (void)in_sizes; (void)n_in; (void)out_size; (void)ws_size;
}

// Round 4
// 476.002 us; speedup vs baseline: 12.1175x; 1.3492x over previous
//
#include <hip/hip_runtime.h>

#define N_NODES 50000
#define N_EDGES 600000
#define D 128
#define NLAYERS 5
#define EPS 1e-5f

typedef _Float16 f16;
typedef f16 f16x8 __attribute__((ext_vector_type(8)));
typedef f16 f16x4 __attribute__((ext_vector_type(4)));
typedef f16 f16x2 __attribute__((ext_vector_type(2)));
typedef float f32x4 __attribute__((ext_vector_type(4)));

// ---------------- CSR build ----------------

__global__ void deg_kernel(const int* __restrict__ dst, int* __restrict__ deg) {
    int e = blockIdx.x * blockDim.x + threadIdx.x;
    if (e < N_EDGES) atomicAdd(&deg[dst[e]], 1);
}

__global__ __launch_bounds__(1024) void scan_block_kernel(const int* __restrict__ deg,
                                                          int* __restrict__ offsets,
                                                          int* __restrict__ blocksums) {
    __shared__ int tmp[1024];
    int i = blockIdx.x * 1024 + threadIdx.x;
    int v = (i < N_NODES) ? deg[i] : 0;
    tmp[threadIdx.x] = v;
    __syncthreads();
#pragma unroll
    for (int off = 1; off < 1024; off <<= 1) {
        int t = (threadIdx.x >= off) ? tmp[threadIdx.x - off] : 0;
        __syncthreads();
        tmp[threadIdx.x] += t;
        __syncthreads();
    }
    if (i < N_NODES) offsets[i] = tmp[threadIdx.x] - v;  // exclusive
    if (threadIdx.x == 1023) blocksums[blockIdx.x] = tmp[1023];
}

__global__ void scan_sums_kernel(int* __restrict__ blocksums, int nb, int* __restrict__ offsets) {
    if (threadIdx.x == 0 && blockIdx.x == 0) {
        int run = 0;
        for (int i = 0; i < nb; ++i) {
            int t = blocksums[i];
            blocksums[i] = run;
            run += t;
        }
        offsets[N_NODES] = N_EDGES;
    }
}

__global__ __launch_bounds__(1024) void scan_add_kernel(int* __restrict__ offsets,
                                                        const int* __restrict__ blocksums) {
    int i = blockIdx.x * 1024 + threadIdx.x;
    if (i < N_NODES) offsets[i] += blocksums[blockIdx.x];
}

__global__ void scatter_kernel(const int* __restrict__ src, const int* __restrict__ dst,
                               int* __restrict__ cursor, int* __restrict__ sorted_src) {
    int e = blockIdx.x * blockDim.x + threadIdx.x;
    if (e >= N_EDGES) return;
    int t = dst[e];
    int pos = atomicAdd(&cursor[t], 1);
    sorted_src[pos] = src[e];
}

// ---------------- weight convert to MFMA fragment order ----------------
// w1f: per layer [cb=16][kk=4][lane=64][e=8];  n = cb*16+(lane&15), k = kk*32+(lane>>4)*8+e
// w2f: per layer [cb=8 ][kk=8][lane=64][e=8];  n = cb*16+(lane&15), k = kk*32+(lane>>4)*8+e
__global__ void convert_w_kernel(const float* __restrict__ W1, const float* __restrict__ W2,
                                 f16* __restrict__ w1f, f16* __restrict__ w2f) {
    int idx = blockIdx.x * blockDim.x + threadIdx.x;
    if (idx >= NLAYERS * 32768) return;
    int l = idx >> 15, rem = idx & 32767;
    {
        int e = rem & 7, lane = (rem >> 3) & 63, kk = (rem >> 9) & 3, cb = rem >> 11;
        int n = cb * 16 + (lane & 15);
        int k = kk * 32 + (lane >> 4) * 8 + e;
        w1f[idx] = (f16)W1[((size_t)l * D + k) * (2 * D) + n];
    }
    {
        int e = rem & 7, lane = (rem >> 3) & 63, kk = (rem >> 9) & 7, cb = rem >> 12;
        int n = cb * 16 + (lane & 15);
        int k = kk * 32 + (lane >> 4) * 8 + e;
        w2f[idx] = (f16)W2[((size_t)l * 2 * D + k) * D + n];
    }
}

// ---------------- model kernels ----------------

__global__ void embed_kernel(const int* __restrict__ x, const float* __restrict__ emb,
                             f16* __restrict__ h_h) {
    int idx = blockIdx.x * blockDim.x + threadIdx.x;  // one 8-elem chunk
    if (idx >= N_NODES * (D / 8)) return;
    int n = idx >> 4;   // D/8 = 16
    int d8 = idx & 15;
    const float* e = emb + x[n] * D + d8 * 8;
    f16x8 v;
#pragma unroll
    for (int j = 0; j < 8; ++j) v[j] = (f16)e[j];
    *(f16x8*)(h_h + (size_t)n * D + d8 * 8) = v;
}

// pull aggregation: agg_h[n] = (f16)( h_h[n] + sum_{s in in(n)} h_h[s] ), fp32 accum
__global__ __launch_bounds__(256) void agg_kernel(const int* __restrict__ offsets,
                                                  const int* __restrict__ sorted_src,
                                                  const f16* __restrict__ h_h,
                                                  f16* __restrict__ agg_h) {
    int node = blockIdx.x * 4 + (threadIdx.x >> 6);
    if (node >= N_NODES) return;
    int lane = threadIdx.x & 63;
    f16x2 hv = *(const f16x2*)(h_h + (size_t)node * D + lane * 2);
    float sx = (float)hv[0], sy = (float)hv[1];  // self loop
    int j = offsets[node];
    const int end = offsets[node + 1];
    for (; j + 4 <= end; j += 4) {
        int s0 = sorted_src[j + 0];
        int s1 = sorted_src[j + 1];
        int s2 = sorted_src[j + 2];
        int s3 = sorted_src[j + 3];
        f16x2 a = *(const f16x2*)(h_h + (size_t)s0 * D + lane * 2);
        f16x2 b = *(const f16x2*)(h_h + (size_t)s1 * D + lane * 2);
        f16x2 c = *(const f16x2*)(h_h + (size_t)s2 * D + lane * 2);
        f16x2 d = *(const f16x2*)(h_h + (size_t)s3 * D + lane * 2);
        sx += (float)a[0] + (float)b[0] + (float)c[0] + (float)d[0];
        sy += (float)a[1] + (float)b[1] + (float)c[1] + (float)d[1];
    }
    for (; j < end; ++j) {
        f16x2 a = *(const f16x2*)(h_h + (size_t)sorted_src[j] * D + lane * 2);
        sx += (float)a[0];
        sy += (float)a[1];
    }
    f16x2 o;
    o[0] = (f16)sx;
    o[1] = (f16)sy;
    *(f16x2*)(agg_h + (size_t)node * D + lane * 2) = o;
}

__device__ __forceinline__ void gload_lds16(const void* g, void* l) {
    __builtin_amdgcn_global_load_lds((const __attribute__((address_space(1))) void*)g,
                                     (__attribute__((address_space(3))) void*)l, 16, 0, 0);
}

// Fused GIN MLP: z2 = (relu(agg @ W1 + b1)) @ W2 + b2, plus column stats of z2.
// 256 threads = 4 waves (wr,wc in 2x2); tile = 64 rows.
// Stage1: z1 64x256 (swapped-operand MFMA -> contiguous LDS writes), stage2: z2 64x128.
__global__ __launch_bounds__(256) void fused_mlp(const f16* __restrict__ A,
                                                 const f16* __restrict__ w1f,
                                                 const float* __restrict__ b1,
                                                 const f16* __restrict__ w2f,
                                                 const float* __restrict__ b2,
                                                 float* __restrict__ z2,
                                                 float* __restrict__ stats) {
    __shared__ __align__(16) char smem[32768 + 1024];
    f16* As = (f16*)smem;                   // 64 x 128 halfs, swizzled (16 KB), aliased by z1s
    f16* z1s = (f16*)smem;                  // 64 x 256 halfs, swizzled (32 KB)
    float* sred = (float*)(smem + 32768);   // 256 f32

    const int tid = threadIdx.x;
    const int r0 = blockIdx.x * 64;
    const int lane = tid & 63;
    const int wave = tid >> 6;
    const int wr = wave >> 1, wc = wave & 1;
    const int l15 = lane & 15, l4 = lane >> 4;

    for (int i = tid; i < 256; i += 256) sred[i] = 0.f;

    // ---- stage A tile: global_load_lds, linear LDS dest + pre-swizzled global source ----
#pragma unroll
    for (int it = 0; it < 4; ++it) {
        const int idx = it * 256 + tid;
        const int row = idx >> 4, c = idx & 15;
        const char* gsrc = (const char*)(A + (size_t)(r0 + row) * D) + ((c * 16) ^ ((row & 7) << 4));
        gload_lds16(gsrc, (char*)As + idx * 16);
    }
    __syncthreads();

    // ---- stage 1: z1^T via mfma(W1, A). acc1[fm][cf]: lane holds z1[m=l15][n=cf*16+l4*4+j] ----
    f32x4 acc1[2][8] = {};
#pragma unroll
    for (int kk = 0; kk < 4; ++kk) {
        f16x8 afr[2];
#pragma unroll
        for (int fm = 0; fm < 2; ++fm) {
            const int m = wr * 32 + fm * 16 + l15;
            const int byte = ((m * D + kk * 32 + l4 * 8) * 2) ^ ((m & 7) << 4);
            afr[fm] = *(const f16x8*)((const char*)As + byte);
        }
#pragma unroll
        for (int cf = 0; cf < 8; ++cf) {
            f16x8 w = *(const f16x8*)(w1f + ((((wc * 8 + cf) * 4) + kk) * 64 + lane) * 8);
#pragma unroll
            for (int fm = 0; fm < 2; ++fm)
                acc1[fm][cf] = __builtin_amdgcn_mfma_f32_16x16x32_f16(w, afr[fm], acc1[fm][cf], 0, 0, 0);
        }
    }
    __syncthreads();  // all As reads complete before overwriting with z1s

    // ---- epilogue 1: bias + relu -> f16 -> z1s (contiguous 8B writes, swizzled) ----
#pragma unroll
    for (int fm = 0; fm < 2; ++fm) {
        const int m = wr * 32 + fm * 16 + l15;
#pragma unroll
        for (int cf = 0; cf < 8; ++cf) {
            const int n = wc * 128 + cf * 16 + l4 * 4;
            const float4 bb = *(const float4*)(b1 + n);
            f16x4 v;
            v[0] = (f16)fmaxf(acc1[fm][cf][0] + bb.x, 0.f);
            v[1] = (f16)fmaxf(acc1[fm][cf][1] + bb.y, 0.f);
            v[2] = (f16)fmaxf(acc1[fm][cf][2] + bb.z, 0.f);
            v[3] = (f16)fmaxf(acc1[fm][cf][3] + bb.w, 0.f);
            const int byte = ((m * 256 + n) * 2) ^ ((m & 7) << 4);
            *(f16x4*)((char*)z1s + byte) = v;
        }
    }
    __syncthreads();

    // ---- stage 2: z2 = z1 @ W2 (non-swapped), 2x4 frags per wave ----
    f32x4 acc2[2][4] = {};
#pragma unroll
    for (int kk = 0; kk < 8; ++kk) {
        f16x8 afr[2];
#pragma unroll
        for (int fm = 0; fm < 2; ++fm) {
            const int m = wr * 32 + fm * 16 + l15;
            const int byte = ((m * 256 + kk * 32 + l4 * 8) * 2) ^ ((m & 7) << 4);
            afr[fm] = *(const f16x8*)((const char*)z1s + byte);
        }
#pragma unroll
        for (int cf = 0; cf < 4; ++cf) {
            f16x8 w = *(const f16x8*)(w2f + ((((wc * 4 + cf) * 8) + kk) * 64 + lane) * 8);
#pragma unroll
            for (int fm = 0; fm < 2; ++fm)
                acc2[fm][cf] = __builtin_amdgcn_mfma_f32_16x16x32_f16(afr[fm], w, acc2[fm][cf], 0, 0, 0);
        }
    }

    // ---- epilogue 2: bias, store f32, column stats ----
    float bv[4];
#pragma unroll
    for (int cf = 0; cf < 4; ++cf) bv[cf] = b2[wc * 64 + cf * 16 + l15];

    float cs[4], cq[4];
#pragma unroll
    for (int cf = 0; cf < 4; ++cf) { cs[cf] = 0.f; cq[cf] = 0.f; }
#pragma unroll
    for (int fm = 0; fm < 2; ++fm)
#pragma unroll
        for (int cf = 0; cf < 4; ++cf) {
            const int col = wc * 64 + cf * 16 + l15;
#pragma unroll
            for (int j = 0; j < 4; ++j) {
                const int row = r0 + wr * 32 + fm * 16 + l4 * 4 + j;
                if (row < N_NODES) {
                    float z = acc2[fm][cf][j] + bv[cf];
                    z2[(size_t)row * D + col] = z;
                    cs[cf] += z;
                    cq[cf] += z * z;
                }
            }
        }
#pragma unroll
    for (int cf = 0; cf < 4; ++cf) {
        float s = cs[cf], q = cq[cf];
        s += __shfl_xor(s, 16, 64);
        q += __shfl_xor(q, 16, 64);
        s += __shfl_xor(s, 32, 64);
        q += __shfl_xor(q, 32, 64);
        if (l4 == 0) {
            const int col = wc * 64 + cf * 16 + l15;
            atomicAdd(&sred[col], s);
            atomicAdd(&sred[D + col], q);
        }
    }
    __syncthreads();
    for (int i = tid; i < 256; i += 256) atomicAdd(&stats[i], sred[i]);
}

// BatchNorm (training stats); !LAST: relu -> h_h (f16). LAST: no relu -> h (f32, d_out).
template <bool LAST>
__global__ void bn_kernel(const float* __restrict__ z, const float* __restrict__ stats,
                          const float* __restrict__ gamma, const float* __restrict__ beta,
                          float* __restrict__ hout, f16* __restrict__ h_h) {
    int idx = blockIdx.x * blockDim.x + threadIdx.x;  // one float4
    if (idx >= N_NODES * (D / 4)) return;
    int d4 = idx & 31;
    float4 zv = *(const float4*)(z + (size_t)idx * 4);
    float4 s = *(const float4*)(stats + d4 * 4);
    float4 sq = *(const float4*)(stats + D + d4 * 4);
    float4 g = *(const float4*)(gamma + d4 * 4);
    float4 b = *(const float4*)(beta + d4 * 4);
    const float invN = 1.0f / (float)N_NODES;
    float zz[4] = {zv.x, zv.y, zv.z, zv.w};
    float ss[4] = {s.x, s.y, s.z, s.w};
    float qq[4] = {sq.x, sq.y, sq.z, sq.w};
    float gg[4] = {g.x, g.y, g.z, g.w};
    float bb[4] = {b.x, b.y, b.z, b.w};
    float o[4];
#pragma unroll
    for (int j = 0; j < 4; ++j) {
        float m = ss[j] * invN;
        float var = qq[j] * invN - m * m;
        float r = rsqrtf(var + EPS);
        o[j] = gg[j] * (zz[j] - m) * r + bb[j];
    }
    if constexpr (LAST) {
        *(float4*)(hout + (size_t)idx * 4) = make_float4(o[0], o[1], o[2], o[3]);
    } else {
        f16x4 v;
#pragma unroll
        for (int j = 0; j < 4; ++j) v[j] = (f16)fmaxf(o[j], 0.f);
        *(f16x4*)(h_h + (size_t)idx * 4) = v;
    }
}

extern "C" void kernel_launch(void* const* d_in, const int* in_sizes, int n_in,
                              void* d_out, int out_size, void* d_ws, size_t ws_size,
                              hipStream_t stream) {
    const int* x_nodes = (const int*)d_in[0];
    const int* src = (const int*)d_in[1];
    const int* dst = (const int*)d_in[2];
    const float* emb = (const float*)d_in[3];
    const float* W1 = (const float*)d_in[4];
    const float* b1 = (const float*)d_in[5];
    const float* W2 = (const float*)d_in[6];
    const float* b2 = (const float*)d_in[7];
    const float* gamma = (const float*)d_in[8];
    const float* beta = (const float*)d_in[9];

    float* h = (float*)d_out;  // final fp32 output

    // workspace layout (no aliasing)
    float* z2 = (float*)d_ws;                                   // N*D f32
    f16* agg_h = (f16*)(z2 + (size_t)N_NODES * D);              // N*D f16
    f16* h_h = agg_h + (size_t)N_NODES * D;                     // N*D f16
    f16* w1f = h_h + (size_t)N_NODES * D;                       // L*32768 f16
    f16* w2f = w1f + (size_t)NLAYERS * 2 * D * D;               // L*32768 f16
    float* stats = (float*)(w2f + (size_t)NLAYERS * 2 * D * D); // 256 f32
    int* deg = (int*)(stats + 2 * D);                           // N
    int* offsets = deg + N_NODES;                               // N+1
    int* cursor = offsets + N_NODES + 1;                        // N
    int* blocksums = cursor + N_NODES;                          // 64
    int* sorted_src = blocksums + 64;                           // E

    dim3 blk(256);
    const int nb_scan = (N_NODES + 1023) / 1024;  // 49
    const int nb_edge = (N_EDGES + 255) / 256;

    // ---- one-time per call: weights + CSR ----
    convert_w_kernel<<<(NLAYERS * 32768 + 255) / 256, blk, 0, stream>>>(W1, W2, w1f, w2f);
    hipMemsetAsync(deg, 0, N_NODES * sizeof(int), stream);
    deg_kernel<<<nb_edge, blk, 0, stream>>>(dst, deg);
    scan_block_kernel<<<nb_scan, 1024, 0, stream>>>(deg, offsets, blocksums);
    scan_sums_kernel<<<1, 64, 0, stream>>>(blocksums, nb_scan, offsets);
    scan_add_kernel<<<nb_scan, 1024, 0, stream>>>(offsets, blocksums);
    hipMemcpyAsync(cursor, offsets, N_NODES * sizeof(int), hipMemcpyDeviceToDevice, stream);
    scatter_kernel<<<nb_edge, blk, 0, stream>>>(src, dst, cursor, sorted_src);

    // ---- model ----
    embed_kernel<<<(N_NODES * 16 + 255) / 256, blk, 0, stream>>>(x_nodes, emb, h_h);

    const int gx = (N_NODES + 63) / 64;  // 782
    for (int l = 0; l < NLAYERS; ++l) {
        agg_kernel<<<(N_NODES + 3) / 4, blk, 0, stream>>>(offsets, sorted_src, h_h, agg_h);
        hipMemsetAsync(stats, 0, 2 * D * sizeof(float), stream);
        fused_mlp<<<gx, blk, 0, stream>>>(agg_h, w1f + (size_t)l * 32768, b1 + l * 2 * D,
                                          w2f + (size_t)l * 32768, b2 + l * D, z2, stats);
        if (l < NLAYERS - 1) {
            bn_kernel<false><<<(N_NODES * 32 + 255) / 256, blk, 0, stream>>>(
                z2, stats, gamma + l * D, beta + l * D, nullptr, h_h);
        } else {
            bn_kernel<true><<<(N_NODES * 32 + 255) / 256, blk, 0, stream>>>(
                z2, stats, gamma + l * D, beta + l * D, h, nullptr);
        }
    }
    (void)in_sizes; (void)n_in; (void)out_size; (void)ws_size;
}